// Round 8
// baseline (435.649 us; speedup 1.0000x reference)
//
#include <hip/hip_runtime.h>

// Problem constants
#define BB   2
#define HH   256
#define WW   256
#define HWSZ (HH * WW)        // 65536
#define CC   24
#define KSZ  7
#define KK   49               // 7*7
#define PADK 3
#define G    8                // channel groups
#define CPG  3                // channels per group
#define LSTR 24               // src halo row stride (22 padded to 24)
#define CSTR (22 * LSTR)      // channel stride in lsrc (floats)
#define LOG2E 1.44269504088896340736f

typedef __attribute__((ext_vector_type(8))) short short8;
typedef __attribute__((ext_vector_type(4))) float float4v;

// float -> bf16 bits (round-to-nearest-even) and back
__device__ __forceinline__ short f2bf(float x) {
  unsigned u = __builtin_bit_cast(unsigned, x);
  unsigned r = u + 0x7FFFu + ((u >> 16) & 1u);
  return (short)(r >> 16);
}
__device__ __forceinline__ float bf2f(short h) {
  unsigned u = ((unsigned)(unsigned short)h) << 16;
  return __builtin_bit_cast(float, u);
}

// ---------------------------------------------------------------------------
// Merged setup (one dispatch):
// blocks 0..191: split-bf16 W fragments, pre-scaled by log2e (exp2 epilogue).
//   wsW[blk][row 16][k 32], blk = ((g*3+c)*4+mt)*2+s   (192 x 512 shorts)
//   row = m (tap row kk = mt*16+row), k = 0..26 conv wts, 27 = bias, 28..31 = 0.
// blocks 192..703: split-bf16 B fragments (texture patch matrix), identical
//   for all 4 diffusion dispatches. int4 idx = ((((b*256+tile)*4+wv)*4+nt)*2+s)*64+lane.
// ---------------------------------------------------------------------------
__global__ __launch_bounds__(256) void k_setup(
    const float* __restrict__ w_kp, const float* __restrict__ b_kp,
    const float* __restrict__ tex, short* __restrict__ wsW,
    short* __restrict__ wsB) {
  __shared__ float lt[3 * 324];   // 18x18 tex halo
  __shared__ int lltk[32];        // k -> tex-halo offset
  int blk = blockIdx.x;
  if (blk < 192) {
    int s = blk & 1, mt = (blk >> 1) & 3, cg = blk >> 3;   // cg = g*3+c
    for (int idx = threadIdx.x; idx < 512; idx += 256) {
      int row = idx >> 5, k = idx & 31;
      int kk = mt * 16 + row;
      float v = 0.f;
      if (kk < KK && k < 28)
        v = ((k < 27) ? w_kp[((size_t)cg * KK + kk) * 27 + k]
                      : b_kp[cg * KK + kk]) * LOG2E;
      short hi = f2bf(v);
      short h = (s == 0) ? hi : f2bf(v - bf2f(hi));
      wsW[(size_t)blk * 512 + idx] = h;
    }
    return;
  }
  int tb = blk - 192;                     // 0..511
  int b = tb >> 8, tile = tb & 255;
  int y0 = (tile >> 4) * 16, x0 = (tile & 15) * 16;
  int tid = threadIdx.x, lane = tid & 63, wv = tid >> 6;
  int q = lane >> 4, col = lane & 15;

  if (tid < 32) {
    int k = tid, v;
    if (k < 27) v = (k / 9) * 324 + ((k % 9) / 3) * 18 + (k % 3);
    else if (k == 27) v = -1;     // bias slot: patch value 1.0
    else v = -2;                  // K padding: 0.0
    lltk[k] = v;
  }
  for (int idx = tid; idx < 972; idx += 256) {
    int ci = idx / 324, r = idx % 324;
    int iy = r / 18, ix = r % 18;
    int yy = y0 + iy - 1, xx = x0 + ix - 1;
    bool ok = (yy >= 0 && yy < HH && xx >= 0 && xx < WW);
    lt[idx] = ok ? tex[((size_t)b * 3 + ci) * HWSZ + yy * WW + xx] : 0.f;
  }
  __syncthreads();

  int tko[8];
#pragma unroll
  for (int j = 0; j < 8; ++j) tko[j] = lltk[q * 8 + j];
  int4* w4 = (int4*)wsB;
#pragma unroll
  for (int nt = 0; nt < 4; ++nt) {
    short8 hi, lo;
#pragma unroll
    for (int j = 0; j < 8; ++j) {
      int o = tko[j];
      float v = (o == -1) ? 1.f
                          : ((o == -2) ? 0.f : lt[o + (wv * 4 + nt) * 18 + col]);
      short h = f2bf(v);
      hi[j] = h;
      lo[j] = f2bf(v - bf2f(h));
    }
    size_t base = ((((size_t)(b * 256 + tile) * 4 + wv) * 4 + nt) * 2);
    w4[(base + 0) * 64 + lane] = __builtin_bit_cast(int4, hi);
    w4[(base + 1) * 64 + lane] = __builtin_bit_cast(int4, lo);
  }
}

// ---------------------------------------------------------------------------
// One diffusion iteration, split-bf16 MFMA logit conv, exp2 epilogue.
// R8: W fragments staged in LDS (ds_read_b128 + immediate offsets — no
// global-load latency in the loop); np UNROLLED into the (mt) body (4
// independent MFMA chains, A amortized 2x); c-loop ROLLED (spill guard);
// 16 precomputed tap pointers bumped once per c — near-zero per-iteration
// address VALU. FINAL accumulates to out via atomicAdd (out pre-init b_td).
// ---------------------------------------------------------------------------
template <bool FIRST, bool FINAL>
__global__ __launch_bounds__(256, 4) void k_diffuse_m(
    const float* __restrict__ depth, const float* __restrict__ src,
    const float* __restrict__ invZ, const float* __restrict__ w_dp,
    const float* __restrict__ b_dp, const short* __restrict__ wsW,
    const short* __restrict__ wsB, float* __restrict__ dst,
    float* __restrict__ part, const float* __restrict__ w_td,
    float* __restrict__ outp) {
  __shared__ __align__(16) short lw[24 * 512];   // 24576 B (group W frags)
  __shared__ float lsrc[CPG * CSTR];             // 6336 B
  __shared__ float ldp[FIRST ? 576 : 4];         // depth halo (FIRST only)
  __shared__ int loffs[64];                      // tap row -> halo offset

  int b = blockIdx.z / G, g = blockIdx.z % G, c0 = g * CPG;
  int x0 = blockIdx.x * 16, y0 = blockIdx.y * 16;
  int tile = blockIdx.y * 16 + blockIdx.x;
  int tid = threadIdx.x, lane = tid & 63, wv = tid >> 6;
  int q = lane >> 4, col = lane & 15;

  // ---- phase A: tables, W->LDS copy, depth halo; B prefetch to regs ----
  if (tid < 64)
    loffs[tid] = (tid < KK) ? ((tid / 7) - 3) * LSTR + ((tid % 7) - 3) : 0;
  {
    const int4* s4 = (const int4*)(wsW + (size_t)g * 12288);
    int4* d4 = (int4*)lw;
#pragma unroll
    for (int i = 0; i < 6; ++i) d4[tid + i * 256] = s4[tid + i * 256];
  }
  if (FIRST) {
    for (int idx = tid; idx < 576; idx += 256) {  // depth halo 24x24 @(-4,-4)
      int iy = idx / 24, ix = idx % 24;
      int yy = y0 + iy - 4, xx = x0 + ix - 4;
      bool ok = (yy >= 0 && yy < HH && xx >= 0 && xx < WW);
      ldp[idx] = ok ? depth[(size_t)b * HWSZ + yy * WW + xx] : 0.f;
    }
  }
  // B fragments (global, L2-hot): issue early, consume after 2nd barrier
  const int4* wB = (const int4*)wsB + ((size_t)(b * 256 + tile) * 4 + wv) * 512;
  short8 Bh[4], Bl[4];
#pragma unroll
  for (int u = 0; u < 4; ++u) {
    Bh[u] = __builtin_bit_cast(short8, wB[(u * 2 + 0) * 64 + lane]);
    Bl[u] = __builtin_bit_cast(short8, wB[(u * 2 + 1) * 64 + lane]);
  }
  __syncthreads();

  // ---- phase B: src halo staging (22x22 @(-3,-3)) ----
  for (int idx = tid; idx < 484; idx += 256) {
    int iy = idx / 22, ix = idx % 22;
    int yy = y0 + iy - PADK, xx = x0 + ix - PADK;
    bool ok = (yy >= 0 && yy < HH && xx >= 0 && xx < WW);
    if (FIRST) {
#pragma unroll
      for (int c = 0; c < CPG; ++c) {
        float a = b_dp[c0 + c];
#pragma unroll
        for (int dy = 0; dy < 3; ++dy)
#pragma unroll
          for (int dx = 0; dx < 3; ++dx)
            a = fmaf(w_dp[(c0 + c) * 9 + dy * 3 + dx],
                     ldp[(iy + dy) * 24 + (ix + dx)], a);
        lsrc[c * CSTR + iy * LSTR + ix] = ok ? a : 0.f;
      }
    } else {
      float sc = ok ? invZ[b * HWSZ + yy * WW + xx] : 0.f;
#pragma unroll
      for (int c = 0; c < CPG; ++c)
        lsrc[c * CSTR + iy * LSTR + ix] =
            ok ? src[((size_t)b * CC + c0 + c) * HWSZ + yy * WW + xx] * sc : 0.f;
    }
  }
  __syncthreads();

  // ---- precomputed tap pointers (16: j = mt*4 + i), bumped +CSTR per c ----
  const float* tp[16];
  {
    const float* basep = lsrc + (wv * 4 + 3) * LSTR + col + 3;
#pragma unroll
    for (int j = 0; j < 16; ++j)
      tp[j] = basep + loffs[(j >> 2) * 16 + q * 4 + (j & 3)];
  }

  float accc[4] = {0.f, 0.f, 0.f, 0.f};
  float zacc[4] = {0.f, 0.f, 0.f, 0.f};
  float res[4]  = {0.f, 0.f, 0.f, 0.f};
  const short* lA = lw + col * 32 + q * 8;   // + (c*4+mt)*1024 shorts

#pragma unroll 1
  for (int c = 0; c < CPG; ++c) {
#pragma unroll
    for (int mt = 0; mt < 4; ++mt) {
      short8 Ah = *(const short8*)(lA + (mt * 2 + 0) * 512);
      short8 Al = *(const short8*)(lA + (mt * 2 + 1) * 512);
      // taps: tv[j][u], u = pixel row (np*2+t) as immediate row offsets
      float tv[16];
#pragma unroll
      for (int j = 0; j < 4; ++j) {
        const float* t = tp[mt * 4 + j];
#pragma unroll
        for (int u = 0; u < 4; ++u) tv[j * 4 + u] = t[u * LSTR];
      }
      float4v C[4];
#pragma unroll
      for (int u = 0; u < 4; ++u) {
        float4v Cu = {0.f, 0.f, 0.f, 0.f};
        Cu = __builtin_amdgcn_mfma_f32_16x16x32_bf16(Ah, Bh[u], Cu, 0, 0, 0);
        Cu = __builtin_amdgcn_mfma_f32_16x16x32_bf16(Ah, Bl[u], Cu, 0, 0, 0);
        Cu = __builtin_amdgcn_mfma_f32_16x16x32_bf16(Al, Bh[u], Cu, 0, 0, 0);
        C[u] = Cu;
      }
      if (mt < 3) {
#pragma unroll
        for (int u = 0; u < 4; ++u) {
          float e0 = __builtin_amdgcn_exp2f(C[u][0]);
          float e1 = __builtin_amdgcn_exp2f(C[u][1]);
          float e2 = __builtin_amdgcn_exp2f(C[u][2]);
          float e3 = __builtin_amdgcn_exp2f(C[u][3]);
          if (FIRST) zacc[u] += (e0 + e1) + (e2 + e3);
          float a = accc[u];
          a = fmaf(e0, tv[0 * 4 + u], a);
          a = fmaf(e1, tv[1 * 4 + u], a);
          a = fmaf(e2, tv[2 * 4 + u], a);
          a = fmaf(e3, tv[3 * 4 + u], a);
          accc[u] = a;
        }
      } else {
        // only tap row 48 (q==0, reg 0) is real in M-tile 3
#pragma unroll
        for (int u = 0; u < 4; ++u) {
          float e = (q == 0) ? __builtin_amdgcn_exp2f(C[u][0]) : 0.f;
          if (FIRST) zacc[u] += e;
          accc[u] = fmaf(e, tv[0 * 4 + u], accc[u]);
        }
      }
    }
    // channel c complete: reduce across quads, emit
#pragma unroll
    for (int u = 0; u < 4; ++u) {
      float v = accc[u];
      v += __shfl_xor(v, 16, 64);
      v += __shfl_xor(v, 32, 64);
      if (FINAL) {
        res[u] = fmaf(w_td[c0 + c], v, res[u]);
      } else {
        int p = (y0 + wv * 4 + u) * WW + (x0 + col);
        if (lane < 16) dst[((size_t)b * CC + c0 + c) * HWSZ + p] = v;
      }
      accc[u] = 0.f;
    }
    // advance to next channel
    lA += 4096;
#pragma unroll
    for (int j = 0; j < 16; ++j) tp[j] += CSTR;
  }

  // tail: z (FIRST) / fused to_depth atomic accumulate (FINAL)
#pragma unroll
  for (int u = 0; u < 4; ++u) {
    int p = (y0 + wv * 4 + u) * WW + (x0 + col);
    if (FIRST) {
      float z = zacc[u];
      z += __shfl_xor(z, 16, 64);
      z += __shfl_xor(z, 32, 64);
      if (lane < 16) part[(size_t)g * BB * HWSZ + b * HWSZ + p] = z;
    }
    if (FINAL) {
      if (lane < 16) {
        float iz = invZ[b * HWSZ + p];
        atomicAdd(&outp[(size_t)b * HWSZ + p], res[u] * iz);
      }
    }
  }
}

// invZ = 1/sum_g zpart (texture-only -> iteration-invariant); also init
// out = b_td so the FINAL dispatch can accumulate per-group via atomics.
__global__ __launch_bounds__(256) void k_zred(const float* __restrict__ zpart,
                                              float* __restrict__ invZ,
                                              const float* __restrict__ b_td,
                                              float* __restrict__ outp) {
  int t = blockIdx.x * 256 + threadIdx.x;
  float z = 0.f;
#pragma unroll
  for (int g = 0; g < G; ++g) z += zpart[(size_t)g * BB * HWSZ + t];
  invZ[t] = 1.f / z;
  outp[t] = b_td[0];
}

// ---------------------------------------------------------------------------
extern "C" void kernel_launch(void* const* d_in, const int* in_sizes, int n_in,
                              void* d_out, int out_size, void* d_ws, size_t ws_size,
                              hipStream_t stream) {
  const float* depth = (const float*)d_in[0];
  const float* tex   = (const float*)d_in[1];
  const float* w_dp  = (const float*)d_in[2];
  const float* b_dp  = (const float*)d_in[3];
  const float* w_kp  = (const float*)d_in[4];
  const float* b_kp  = (const float*)d_in[5];
  const float* w_td  = (const float*)d_in[6];
  const float* b_td  = (const float*)d_in[7];
  float* out = (float*)d_out;

  // ws: bufA/bufB (12.58 MB ea) + part (4.19 MB) + invZ (0.5 MB)
  //     + wsW (0.2 MB) + wsB (16.78 MB)  => ~47 MB
  char* ws = (char*)d_ws;
  const size_t buf_b = (size_t)BB * CC * HWSZ * 4;
  float* bufA = (float*)ws;
  float* bufB = (float*)(ws + buf_b);
  float* part = (float*)(ws + 2 * buf_b);
  float* invZ = (float*)(ws + 2 * buf_b + (size_t)G * BB * HWSZ * 4);
  short* wsW  = (short*)(ws + 2 * buf_b + (size_t)G * BB * HWSZ * 4 +
                         (size_t)BB * HWSZ * 4);
  short* wsB  = (short*)(ws + 2 * buf_b + (size_t)G * BB * HWSZ * 4 +
                         (size_t)BB * HWSZ * 4 + 192 * 512 * 2);

  k_setup<<<dim3(192 + 512), dim3(256), 0, stream>>>(w_kp, b_kp, tex, wsW, wsB);

  dim3 grid(WW / 16, HH / 16, BB * G), blk(256);
  dim3 grid1(BB * HWSZ / 256), blk1(256);

  // iter1: fused depth_latent; emits unnormalized acc + partial z
  k_diffuse_m<true, false><<<grid, blk, 0, stream>>>(
      depth, nullptr, nullptr, w_dp, b_dp, wsW, wsB, bufB, part, w_td, nullptr);
  k_zred<<<grid1, blk1, 0, stream>>>(part, invZ, b_td, out);
  // iters 2,3: unnormalized ping-pong, invZ folded into staging
  k_diffuse_m<false, false><<<grid, blk, 0, stream>>>(
      depth, bufB, invZ, w_dp, b_dp, wsW, wsB, bufA, part, w_td, nullptr);
  k_diffuse_m<false, false><<<grid, blk, 0, stream>>>(
      depth, bufA, invZ, w_dp, b_dp, wsW, wsB, bufB, part, w_td, nullptr);
  // iter4: fused to_depth, atomic accumulate into out (pre-init by k_zred)
  k_diffuse_m<false, true><<<grid, blk, 0, stream>>>(
      depth, bufB, invZ, w_dp, b_dp, wsW, wsB, nullptr, part, w_td, out);
}

// Round 9
// 280.623 us; speedup vs baseline: 1.5524x; 1.5524x over previous
//
#include <hip/hip_runtime.h>

// Problem constants
#define BB   2
#define HH   256
#define WW   256
#define HWSZ (HH * WW)        // 65536
#define CC   24
#define KSZ  7
#define KK   49               // 7*7
#define PADK 3
#define G    8                // channel groups
#define CPG  3                // channels per group
#define LSTR 24               // src halo row stride (22 padded to 24)
#define CSTR (22 * LSTR)      // channel stride in lsrc (floats)
#define LOG2E 1.44269504088896340736f

typedef __attribute__((ext_vector_type(8))) short short8;
typedef __attribute__((ext_vector_type(4))) float float4v;

// float -> bf16 bits (round-to-nearest-even) and back
__device__ __forceinline__ short f2bf(float x) {
  unsigned u = __builtin_bit_cast(unsigned, x);
  unsigned r = u + 0x7FFFu + ((u >> 16) & 1u);
  return (short)(r >> 16);
}
__device__ __forceinline__ float bf2f(short h) {
  unsigned u = ((unsigned)(unsigned short)h) << 16;
  return __builtin_bit_cast(float, u);
}

// ---------------------------------------------------------------------------
// Merged setup (one dispatch):
// blocks 0..191: split-bf16 W fragments, pre-scaled by log2e (exp2 epilogue).
//   wsW[blk][row 16][k 32], blk = ((g*3+c)*4+mt)*2+s   (192 x 512 shorts)
//   row = m (tap row kk = mt*16+row), k = 0..26 conv wts, 27 = bias, 28..31=0.
// blocks 192..703: split-bf16 B fragments (texture patch matrix), identical
//   for all 4 diffusion dispatches. int4 idx = ((((b*256+tile)*4+wv)*4+nt)*2+s)*64+lane.
// ---------------------------------------------------------------------------
__global__ __launch_bounds__(256) void k_setup(
    const float* __restrict__ w_kp, const float* __restrict__ b_kp,
    const float* __restrict__ tex, short* __restrict__ wsW,
    short* __restrict__ wsB) {
  __shared__ float lt[3 * 324];   // 18x18 tex halo
  __shared__ int lltk[32];        // k -> tex-halo offset
  int blk = blockIdx.x;
  if (blk < 192) {
    int s = blk & 1, mt = (blk >> 1) & 3, cg = blk >> 3;   // cg = g*3+c
    for (int idx = threadIdx.x; idx < 512; idx += 256) {
      int row = idx >> 5, k = idx & 31;
      int kk = mt * 16 + row;
      float v = 0.f;
      if (kk < KK && k < 28)
        v = ((k < 27) ? w_kp[((size_t)cg * KK + kk) * 27 + k]
                      : b_kp[cg * KK + kk]) * LOG2E;
      short hi = f2bf(v);
      short h = (s == 0) ? hi : f2bf(v - bf2f(hi));
      wsW[(size_t)blk * 512 + idx] = h;
    }
    return;
  }
  int tb = blk - 192;                     // 0..511
  int b = tb >> 8, tile = tb & 255;
  int y0 = (tile >> 4) * 16, x0 = (tile & 15) * 16;
  int tid = threadIdx.x, lane = tid & 63, wv = tid >> 6;
  int q = lane >> 4, col = lane & 15;

  if (tid < 32) {
    int k = tid, v;
    if (k < 27) v = (k / 9) * 324 + ((k % 9) / 3) * 18 + (k % 3);
    else if (k == 27) v = -1;     // bias slot: patch value 1.0
    else v = -2;                  // K padding: 0.0
    lltk[k] = v;
  }
  for (int idx = tid; idx < 972; idx += 256) {
    int ci = idx / 324, r = idx % 324;
    int iy = r / 18, ix = r % 18;
    int yy = y0 + iy - 1, xx = x0 + ix - 1;
    bool ok = (yy >= 0 && yy < HH && xx >= 0 && xx < WW);
    lt[idx] = ok ? tex[((size_t)b * 3 + ci) * HWSZ + yy * WW + xx] : 0.f;
  }
  __syncthreads();

  int tko[8];
#pragma unroll
  for (int j = 0; j < 8; ++j) tko[j] = lltk[q * 8 + j];
  int4* w4 = (int4*)wsB;
#pragma unroll
  for (int nt = 0; nt < 4; ++nt) {
    short8 hi, lo;
#pragma unroll
    for (int j = 0; j < 8; ++j) {
      int o = tko[j];
      float v = (o == -1) ? 1.f
                          : ((o == -2) ? 0.f : lt[o + (wv * 4 + nt) * 18 + col]);
      short h = f2bf(v);
      hi[j] = h;
      lo[j] = f2bf(v - bf2f(h));
    }
    size_t base = ((((size_t)(b * 256 + tile) * 4 + wv) * 4 + nt) * 2);
    w4[(base + 0) * 64 + lane] = __builtin_bit_cast(int4, hi);
    w4[(base + 1) * 64 + lane] = __builtin_bit_cast(int4, lo);
  }
}

// ---------------------------------------------------------------------------
// One diffusion iteration, split-bf16 MFMA logit conv, exp2 epilogue.
// R9 = R6/R7 proven shape (np 2-pass, ROLLED 12-iter (c,mt) loop, 2 C-chains
// max — the no-spill envelope confirmed by R3/R8 failures) with ONE change:
// W fragments staged in LDS, so in-loop A reads are ds_read_b128 off a
// bumped pointer (no 200-cy global latency in the loop). Taps consumed
// inline post-MFMA (R6 style). FINAL accumulates to out via atomicAdd
// (out pre-init to b_td by k_zred).
// ---------------------------------------------------------------------------
template <bool FIRST, bool FINAL>
__global__ __launch_bounds__(256, 4) void k_diffuse_m(
    const float* __restrict__ depth, const float* __restrict__ src,
    const float* __restrict__ invZ, const float* __restrict__ w_dp,
    const float* __restrict__ b_dp, const short* __restrict__ wsW,
    const short* __restrict__ wsB, float* __restrict__ dst,
    float* __restrict__ part, const float* __restrict__ w_td,
    float* __restrict__ outp) {
  __shared__ __align__(16) short lw[24 * 512];   // 24576 B (group W frags)
  __shared__ float lsrc[CPG * CSTR];             // 6336 B
  __shared__ float ldp[FIRST ? 576 : 4];         // depth halo (FIRST only)
  __shared__ int loffs[64];                      // tap row -> halo offset

  int b = blockIdx.z / G, g = blockIdx.z % G, c0 = g * CPG;
  int x0 = blockIdx.x * 16, y0 = blockIdx.y * 16;
  int tile = blockIdx.y * 16 + blockIdx.x;
  int tid = threadIdx.x, lane = tid & 63, wv = tid >> 6;
  int q = lane >> 4, col = lane & 15;

  // ---- phase A: tables, W->LDS copy, depth halo ----
  if (tid < 64)
    loffs[tid] = (tid < KK) ? ((tid / 7) - 3) * LSTR + ((tid % 7) - 3) : 0;
  {
    const int4* s4 = (const int4*)(wsW + (size_t)g * 12288);
    int4* d4 = (int4*)lw;
#pragma unroll
    for (int i = 0; i < 6; ++i) d4[tid + i * 256] = s4[tid + i * 256];
  }
  if (FIRST) {
    for (int idx = tid; idx < 576; idx += 256) {  // depth halo 24x24 @(-4,-4)
      int iy = idx / 24, ix = idx % 24;
      int yy = y0 + iy - 4, xx = x0 + ix - 4;
      bool ok = (yy >= 0 && yy < HH && xx >= 0 && xx < WW);
      ldp[idx] = ok ? depth[(size_t)b * HWSZ + yy * WW + xx] : 0.f;
    }
  }
  __syncthreads();

  // ---- phase B: src halo staging (22x22 @(-3,-3)) ----
  for (int idx = tid; idx < 484; idx += 256) {
    int iy = idx / 22, ix = idx % 22;
    int yy = y0 + iy - PADK, xx = x0 + ix - PADK;
    bool ok = (yy >= 0 && yy < HH && xx >= 0 && xx < WW);
    if (FIRST) {
#pragma unroll
      for (int c = 0; c < CPG; ++c) {
        float a = b_dp[c0 + c];
#pragma unroll
        for (int dy = 0; dy < 3; ++dy)
#pragma unroll
          for (int dx = 0; dx < 3; ++dx)
            a = fmaf(w_dp[(c0 + c) * 9 + dy * 3 + dx],
                     ldp[(iy + dy) * 24 + (ix + dx)], a);
        lsrc[c * CSTR + iy * LSTR + ix] = ok ? a : 0.f;
      }
    } else {
      float sc = ok ? invZ[b * HWSZ + yy * WW + xx] : 0.f;
#pragma unroll
      for (int c = 0; c < CPG; ++c)
        lsrc[c * CSTR + iy * LSTR + ix] =
            ok ? src[((size_t)b * CC + c0 + c) * HWSZ + yy * WW + xx] * sc : 0.f;
    }
  }
  __syncthreads();

  const int4* wB = (const int4*)wsB + ((size_t)(b * 256 + tile) * 4 + wv) * 512;

#pragma unroll 1
  for (int np = 0; np < 2; ++np) {
    // B fragments for this pass's 2 pixel rows (precomputed, coalesced b128)
    short8 Bh0 = __builtin_bit_cast(short8, wB[(np * 4 + 0) * 64 + lane]);
    short8 Bl0 = __builtin_bit_cast(short8, wB[(np * 4 + 1) * 64 + lane]);
    short8 Bh1 = __builtin_bit_cast(short8, wB[(np * 4 + 2) * 64 + lane]);
    short8 Bl1 = __builtin_bit_cast(short8, wB[(np * 4 + 3) * 64 + lane]);
    int basep = (wv * 4 + np * 2 + 3) * LSTR + col + 3;  // t=0 pixel in halo
    float zacc[2] = {0.f, 0.f}, res[2] = {0.f, 0.f};
    float accc[2] = {0.f, 0.f};

    const short* lAp = lw + col * 32 + q * 8;   // bumped +1024 shorts per iter
#pragma unroll 1
    for (int idx = 0; idx < 12; ++idx) {
      short8 Ah = *(const short8*)(lAp);
      short8 Al = *(const short8*)(lAp + 512);
      lAp += 1024;
      int c = idx >> 2, mt = idx & 3;
      int mtb = mt * 16 + q * 4;
      const float* lsc = lsrc + c * CSTR + basep;
      const float* p0 = lsc + loffs[mtb + 0];
      const float* p1 = lsc + loffs[mtb + 1];
      const float* p2 = lsc + loffs[mtb + 2];
      const float* p3 = lsc + loffs[mtb + 3];

      float4v C0 = {0.f, 0.f, 0.f, 0.f}, C1 = {0.f, 0.f, 0.f, 0.f};
      C0 = __builtin_amdgcn_mfma_f32_16x16x32_bf16(Ah, Bh0, C0, 0, 0, 0);
      C1 = __builtin_amdgcn_mfma_f32_16x16x32_bf16(Ah, Bh1, C1, 0, 0, 0);
      C0 = __builtin_amdgcn_mfma_f32_16x16x32_bf16(Ah, Bl0, C0, 0, 0, 0);
      C1 = __builtin_amdgcn_mfma_f32_16x16x32_bf16(Ah, Bl1, C1, 0, 0, 0);
      C0 = __builtin_amdgcn_mfma_f32_16x16x32_bf16(Al, Bh0, C0, 0, 0, 0);
      C1 = __builtin_amdgcn_mfma_f32_16x16x32_bf16(Al, Bh1, C1, 0, 0, 0);

      if (mt < 3) {
        float e00 = __builtin_amdgcn_exp2f(C0[0]);
        float e01 = __builtin_amdgcn_exp2f(C0[1]);
        float e02 = __builtin_amdgcn_exp2f(C0[2]);
        float e03 = __builtin_amdgcn_exp2f(C0[3]);
        float e10 = __builtin_amdgcn_exp2f(C1[0]);
        float e11 = __builtin_amdgcn_exp2f(C1[1]);
        float e12 = __builtin_amdgcn_exp2f(C1[2]);
        float e13 = __builtin_amdgcn_exp2f(C1[3]);
        if (FIRST) {
          zacc[0] += (e00 + e01) + (e02 + e03);
          zacc[1] += (e10 + e11) + (e12 + e13);
        }
        float a0 = accc[0], a1 = accc[1];
        a0 = fmaf(e00, p0[0], a0); a1 = fmaf(e10, p0[LSTR], a1);
        a0 = fmaf(e01, p1[0], a0); a1 = fmaf(e11, p1[LSTR], a1);
        a0 = fmaf(e02, p2[0], a0); a1 = fmaf(e12, p2[LSTR], a1);
        a0 = fmaf(e03, p3[0], a0); a1 = fmaf(e13, p3[LSTR], a1);
        accc[0] = a0; accc[1] = a1;
      } else {
        // only tap row 48 (q==0, reg 0) is real in M-tile 3
        float e0 = (q == 0) ? __builtin_amdgcn_exp2f(C0[0]) : 0.f;
        float e1 = (q == 0) ? __builtin_amdgcn_exp2f(C1[0]) : 0.f;
        if (FIRST) { zacc[0] += e0; zacc[1] += e1; }
        accc[0] = fmaf(e0, p0[0], accc[0]);
        accc[1] = fmaf(e1, p0[LSTR], accc[1]);
      }
      if (mt == 3) {
        // channel c complete: reduce across quads, emit
#pragma unroll
        for (int t = 0; t < 2; ++t) {
          float v = accc[t];
          v += __shfl_xor(v, 16, 64);
          v += __shfl_xor(v, 32, 64);
          if (FINAL) {
            res[t] = fmaf(w_td[c0 + c], v, res[t]);
          } else {
            int p = (y0 + wv * 4 + np * 2 + t) * WW + (x0 + col);
            if (lane < 16) dst[((size_t)b * CC + c0 + c) * HWSZ + p] = v;
          }
          accc[t] = 0.f;
        }
      }
    }
    // pass tail: z (FIRST) / fused to_depth atomic accumulate (FINAL)
#pragma unroll
    for (int t = 0; t < 2; ++t) {
      int p = (y0 + wv * 4 + np * 2 + t) * WW + (x0 + col);
      if (FIRST) {
        float z = zacc[t];
        z += __shfl_xor(z, 16, 64);
        z += __shfl_xor(z, 32, 64);
        if (lane < 16) part[(size_t)g * BB * HWSZ + b * HWSZ + p] = z;
      }
      if (FINAL) {
        if (lane < 16) {
          float iz = invZ[b * HWSZ + p];
          atomicAdd(&outp[(size_t)b * HWSZ + p], res[t] * iz);
        }
      }
    }
  }
}

// invZ = 1/sum_g zpart (texture-only -> iteration-invariant); also init
// out = b_td so the FINAL dispatch can accumulate per-group via atomics.
__global__ __launch_bounds__(256) void k_zred(const float* __restrict__ zpart,
                                              float* __restrict__ invZ,
                                              const float* __restrict__ b_td,
                                              float* __restrict__ outp) {
  int t = blockIdx.x * 256 + threadIdx.x;
  float z = 0.f;
#pragma unroll
  for (int g = 0; g < G; ++g) z += zpart[(size_t)g * BB * HWSZ + t];
  invZ[t] = 1.f / z;
  outp[t] = b_td[0];
}

// ---------------------------------------------------------------------------
extern "C" void kernel_launch(void* const* d_in, const int* in_sizes, int n_in,
                              void* d_out, int out_size, void* d_ws, size_t ws_size,
                              hipStream_t stream) {
  const float* depth = (const float*)d_in[0];
  const float* tex   = (const float*)d_in[1];
  const float* w_dp  = (const float*)d_in[2];
  const float* b_dp  = (const float*)d_in[3];
  const float* w_kp  = (const float*)d_in[4];
  const float* b_kp  = (const float*)d_in[5];
  const float* w_td  = (const float*)d_in[6];
  const float* b_td  = (const float*)d_in[7];
  float* out = (float*)d_out;

  // ws: bufA/bufB (12.58 MB ea) + part (4.19 MB) + invZ (0.5 MB)
  //     + wsW (0.2 MB) + wsB (16.78 MB)  => ~47 MB
  char* ws = (char*)d_ws;
  const size_t buf_b = (size_t)BB * CC * HWSZ * 4;
  float* bufA = (float*)ws;
  float* bufB = (float*)(ws + buf_b);
  float* part = (float*)(ws + 2 * buf_b);
  float* invZ = (float*)(ws + 2 * buf_b + (size_t)G * BB * HWSZ * 4);
  short* wsW  = (short*)(ws + 2 * buf_b + (size_t)G * BB * HWSZ * 4 +
                         (size_t)BB * HWSZ * 4);
  short* wsB  = (short*)(ws + 2 * buf_b + (size_t)G * BB * HWSZ * 4 +
                         (size_t)BB * HWSZ * 4 + 192 * 512 * 2);

  k_setup<<<dim3(192 + 512), dim3(256), 0, stream>>>(w_kp, b_kp, tex, wsW, wsB);

  dim3 grid(WW / 16, HH / 16, BB * G), blk(256);
  dim3 grid1(BB * HWSZ / 256), blk1(256);

  // iter1: fused depth_latent; emits unnormalized acc + partial z
  k_diffuse_m<true, false><<<grid, blk, 0, stream>>>(
      depth, nullptr, nullptr, w_dp, b_dp, wsW, wsB, bufB, part, w_td, nullptr);
  k_zred<<<grid1, blk1, 0, stream>>>(part, invZ, b_td, out);
  // iters 2,3: unnormalized ping-pong, invZ folded into staging
  k_diffuse_m<false, false><<<grid, blk, 0, stream>>>(
      depth, bufB, invZ, w_dp, b_dp, wsW, wsB, bufA, part, w_td, nullptr);
  k_diffuse_m<false, false><<<grid, blk, 0, stream>>>(
      depth, bufA, invZ, w_dp, b_dp, wsW, wsB, bufB, part, w_td, nullptr);
  // iter4: fused to_depth, atomic accumulate into out (pre-init by k_zred)
  k_diffuse_m<false, true><<<grid, blk, 0, stream>>>(
      depth, bufB, invZ, w_dp, b_dp, wsW, wsB, nullptr, part, w_td, out);
}

// Round 10
// 255.649 us; speedup vs baseline: 1.7041x; 1.0977x over previous
//
#include <hip/hip_runtime.h>

// Problem constants
#define BB   2
#define HH   256
#define WW   256
#define HWSZ (HH * WW)        // 65536
#define CC   24
#define KSZ  7
#define KK   49               // 7*7
#define PADK 3
#define G    8                // channel groups
#define CPG  3                // channels per group
#define LSTR 24               // src halo row stride (22 padded to 24)
#define CSTR (22 * LSTR)      // channel stride in lsrc (floats)
#define LOG2E 1.44269504088896340736f

typedef __attribute__((ext_vector_type(8))) short short8;
typedef __attribute__((ext_vector_type(4))) float float4v;

// float -> bf16 bits (round-to-nearest-even) and back
__device__ __forceinline__ short f2bf(float x) {
  unsigned u = __builtin_bit_cast(unsigned, x);
  unsigned r = u + 0x7FFFu + ((u >> 16) & 1u);
  return (short)(r >> 16);
}
__device__ __forceinline__ float bf2f(short h) {
  unsigned u = ((unsigned)(unsigned short)h) << 16;
  return __builtin_bit_cast(float, u);
}

// ---------------------------------------------------------------------------
// Merged setup (one dispatch):
// blocks 0..191: split-bf16 W fragments in FRAG-MAJOR (consumer-lane) order:
//   wsW[blk][lane*8+j] = W[m=lane&15][k=(lane>>4)*8+j], pre-scaled by log2e.
//   blk = ((g*3+c)*4+mt)*2+s. Lane-contiguous 16B => conflict-free b128 reads.
// blocks 192..703: split-bf16 B fragments (texture patch matrix), identical
//   for all 4 diffusion dispatches. int4 idx = ((((b*256+tile)*4+wv)*4+nt)*2+s)*64+lane.
// ---------------------------------------------------------------------------
__global__ __launch_bounds__(256) void k_setup(
    const float* __restrict__ w_kp, const float* __restrict__ b_kp,
    const float* __restrict__ tex, short* __restrict__ wsW,
    short* __restrict__ wsB) {
  __shared__ float lt[3 * 324];   // 18x18 tex halo
  __shared__ int lltk[32];        // k -> tex-halo offset
  int blk = blockIdx.x;
  if (blk < 192) {
    int s = blk & 1, mt = (blk >> 1) & 3, cg = blk >> 3;   // cg = g*3+c
    for (int idx = threadIdx.x; idx < 512; idx += 256) {
      int l = idx >> 3, j = idx & 7;          // consumer lane, reg element
      int kk = mt * 16 + (l & 15);            // tap row (A row m = col)
      int k = (l >> 4) * 8 + j;               // K index (q*8+j)
      float v = 0.f;
      if (kk < KK && k < 28)
        v = ((k < 27) ? w_kp[((size_t)cg * KK + kk) * 27 + k]
                      : b_kp[cg * KK + kk]) * LOG2E;
      short hi = f2bf(v);
      short h = (s == 0) ? hi : f2bf(v - bf2f(hi));
      wsW[(size_t)blk * 512 + idx] = h;
    }
    return;
  }
  int tb = blk - 192;                     // 0..511
  int b = tb >> 8, tile = tb & 255;
  int y0 = (tile >> 4) * 16, x0 = (tile & 15) * 16;
  int tid = threadIdx.x, lane = tid & 63, wv = tid >> 6;
  int q = lane >> 4, col = lane & 15;

  if (tid < 32) {
    int k = tid, v;
    if (k < 27) v = (k / 9) * 324 + ((k % 9) / 3) * 18 + (k % 3);
    else if (k == 27) v = -1;     // bias slot: patch value 1.0
    else v = -2;                  // K padding: 0.0
    lltk[k] = v;
  }
  for (int idx = tid; idx < 972; idx += 256) {
    int ci = idx / 324, r = idx % 324;
    int iy = r / 18, ix = r % 18;
    int yy = y0 + iy - 1, xx = x0 + ix - 1;
    bool ok = (yy >= 0 && yy < HH && xx >= 0 && xx < WW);
    lt[idx] = ok ? tex[((size_t)b * 3 + ci) * HWSZ + yy * WW + xx] : 0.f;
  }
  __syncthreads();

  int tko[8];
#pragma unroll
  for (int j = 0; j < 8; ++j) tko[j] = lltk[q * 8 + j];
  int4* w4 = (int4*)wsB;
#pragma unroll
  for (int nt = 0; nt < 4; ++nt) {
    short8 hi, lo;
#pragma unroll
    for (int j = 0; j < 8; ++j) {
      int o = tko[j];
      float v = (o == -1) ? 1.f
                          : ((o == -2) ? 0.f : lt[o + (wv * 4 + nt) * 18 + col]);
      short h = f2bf(v);
      hi[j] = h;
      lo[j] = f2bf(v - bf2f(h));
    }
    size_t base = ((((size_t)(b * 256 + tile) * 4 + wv) * 4 + nt) * 2);
    w4[(base + 0) * 64 + lane] = __builtin_bit_cast(int4, hi);
    w4[(base + 1) * 64 + lane] = __builtin_bit_cast(int4, lo);
  }
}

// ---------------------------------------------------------------------------
// One diffusion iteration, split-bf16 MFMA logit conv, exp2 epilogue.
// R10 LDS-pipe fixes: (1) frag-major lw -> conflict-free ds_read_b128 A
// reads at lane*16B; (2) tap offsets computed arithmetically into 16
// registers (no in-loop LDS table); (3) mt UNROLLED (constant offs[] index,
// base+immediate tap pairs -> ds_read2 mergeable), c ROLLED (spill guard,
// 2 C-chains structural liveness). FINAL accumulates to out via atomicAdd.
// ---------------------------------------------------------------------------
template <bool FIRST, bool FINAL>
__global__ __launch_bounds__(256, 4) void k_diffuse_m(
    const float* __restrict__ depth, const float* __restrict__ src,
    const float* __restrict__ invZ, const float* __restrict__ w_dp,
    const float* __restrict__ b_dp, const short* __restrict__ wsW,
    const short* __restrict__ wsB, float* __restrict__ dst,
    float* __restrict__ part, const float* __restrict__ w_td,
    float* __restrict__ outp) {
  __shared__ __align__(16) short lw[24 * 512];   // 24576 B (group W frags)
  __shared__ float lsrc[CPG * CSTR];             // 6336 B
  __shared__ float ldp[FIRST ? 576 : 4];         // depth halo (FIRST only)

  int b = blockIdx.z / G, g = blockIdx.z % G, c0 = g * CPG;
  int x0 = blockIdx.x * 16, y0 = blockIdx.y * 16;
  int tile = blockIdx.y * 16 + blockIdx.x;
  int tid = threadIdx.x, lane = tid & 63, wv = tid >> 6;
  int q = lane >> 4, col = lane & 15;

  // ---- phase A: W->LDS copy (layout-preserving), depth halo ----
  {
    const int4* s4 = (const int4*)(wsW + (size_t)g * 12288);
    int4* d4 = (int4*)lw;
#pragma unroll
    for (int i = 0; i < 6; ++i) d4[tid + i * 256] = s4[tid + i * 256];
  }
  if (FIRST) {
    for (int idx = tid; idx < 576; idx += 256) {  // depth halo 24x24 @(-4,-4)
      int iy = idx / 24, ix = idx % 24;
      int yy = y0 + iy - 4, xx = x0 + ix - 4;
      bool ok = (yy >= 0 && yy < HH && xx >= 0 && xx < WW);
      ldp[idx] = ok ? depth[(size_t)b * HWSZ + yy * WW + xx] : 0.f;
    }
  }
  __syncthreads();

  // ---- phase B: src halo staging (22x22 @(-3,-3)) ----
  for (int idx = tid; idx < 484; idx += 256) {
    int iy = idx / 22, ix = idx % 22;
    int yy = y0 + iy - PADK, xx = x0 + ix - PADK;
    bool ok = (yy >= 0 && yy < HH && xx >= 0 && xx < WW);
    if (FIRST) {
#pragma unroll
      for (int c = 0; c < CPG; ++c) {
        float a = b_dp[c0 + c];
#pragma unroll
        for (int dy = 0; dy < 3; ++dy)
#pragma unroll
          for (int dx = 0; dx < 3; ++dx)
            a = fmaf(w_dp[(c0 + c) * 9 + dy * 3 + dx],
                     ldp[(iy + dy) * 24 + (ix + dx)], a);
        lsrc[c * CSTR + iy * LSTR + ix] = ok ? a : 0.f;
      }
    } else {
      float sc = ok ? invZ[b * HWSZ + yy * WW + xx] : 0.f;
#pragma unroll
      for (int c = 0; c < CPG; ++c)
        lsrc[c * CSTR + iy * LSTR + ix] =
            ok ? src[((size_t)b * CC + c0 + c) * HWSZ + yy * WW + xx] * sc : 0.f;
    }
  }
  __syncthreads();

  // ---- per-lane tap offsets in registers (j = mt*4 + i, constant-indexed)
  // tap t = mt*16 + q*4 + i; off = (t/7-3)*LSTR + (t%7-3) = t + 17*(t/7) - 75.
  // t/7 == (t*37)>>8 exactly for t<=62. Pad taps (t>48) clamp to 48: their
  // e is forced to 0 in the mt==3 path, the read just needs to be in-bounds.
  int offs[16];
#pragma unroll
  for (int j = 0; j < 16; ++j) {
    int t = (j >> 2) * 16 + q * 4 + (j & 3);
    t = (t < 48) ? t : 48;
    int dy = (t * 37) >> 8;
    offs[j] = t + 17 * dy - 75;
  }

  const short* lA = lw + lane * 8;   // + ((c*4+mt)*2+s)*512 shorts
  const int4* wB = (const int4*)wsB + ((size_t)(b * 256 + tile) * 4 + wv) * 512;

#pragma unroll 1
  for (int np = 0; np < 2; ++np) {
    // B fragments for this pass's 2 pixel rows (precomputed, coalesced b128)
    short8 Bh0 = __builtin_bit_cast(short8, wB[(np * 4 + 0) * 64 + lane]);
    short8 Bl0 = __builtin_bit_cast(short8, wB[(np * 4 + 1) * 64 + lane]);
    short8 Bh1 = __builtin_bit_cast(short8, wB[(np * 4 + 2) * 64 + lane]);
    short8 Bl1 = __builtin_bit_cast(short8, wB[(np * 4 + 3) * 64 + lane]);
    const float* base = lsrc + (wv * 4 + np * 2 + 3) * LSTR + col + 3;
    float zacc[2] = {0.f, 0.f}, res[2] = {0.f, 0.f};
    float accc[2] = {0.f, 0.f};

#pragma unroll 1
    for (int c = 0; c < CPG; ++c) {
      const short* lAc = lA + c * 2048;   // c*4 frags * 512 shorts
#pragma unroll
      for (int mt = 0; mt < 4; ++mt) {
        short8 Ah = *(const short8*)(lAc + mt * 1024);
        short8 Al = *(const short8*)(lAc + mt * 1024 + 512);

        float4v C0 = {0.f, 0.f, 0.f, 0.f}, C1 = {0.f, 0.f, 0.f, 0.f};
        C0 = __builtin_amdgcn_mfma_f32_16x16x32_bf16(Ah, Bh0, C0, 0, 0, 0);
        C1 = __builtin_amdgcn_mfma_f32_16x16x32_bf16(Ah, Bh1, C1, 0, 0, 0);
        C0 = __builtin_amdgcn_mfma_f32_16x16x32_bf16(Ah, Bl0, C0, 0, 0, 0);
        C1 = __builtin_amdgcn_mfma_f32_16x16x32_bf16(Ah, Bl1, C1, 0, 0, 0);
        C0 = __builtin_amdgcn_mfma_f32_16x16x32_bf16(Al, Bh0, C0, 0, 0, 0);
        C1 = __builtin_amdgcn_mfma_f32_16x16x32_bf16(Al, Bh1, C1, 0, 0, 0);

        if (mt < 3) {
          // tap pairs at base[off] / base[off+LSTR]: immediate-delta pairs
          const float* t0 = base + offs[mt * 4 + 0];
          const float* t1 = base + offs[mt * 4 + 1];
          const float* t2 = base + offs[mt * 4 + 2];
          const float* t3 = base + offs[mt * 4 + 3];
          float e00 = __builtin_amdgcn_exp2f(C0[0]);
          float e01 = __builtin_amdgcn_exp2f(C0[1]);
          float e02 = __builtin_amdgcn_exp2f(C0[2]);
          float e03 = __builtin_amdgcn_exp2f(C0[3]);
          float e10 = __builtin_amdgcn_exp2f(C1[0]);
          float e11 = __builtin_amdgcn_exp2f(C1[1]);
          float e12 = __builtin_amdgcn_exp2f(C1[2]);
          float e13 = __builtin_amdgcn_exp2f(C1[3]);
          if (FIRST) {
            zacc[0] += (e00 + e01) + (e02 + e03);
            zacc[1] += (e10 + e11) + (e12 + e13);
          }
          float a0 = accc[0], a1 = accc[1];
          a0 = fmaf(e00, t0[0], a0); a1 = fmaf(e10, t0[LSTR], a1);
          a0 = fmaf(e01, t1[0], a0); a1 = fmaf(e11, t1[LSTR], a1);
          a0 = fmaf(e02, t2[0], a0); a1 = fmaf(e12, t2[LSTR], a1);
          a0 = fmaf(e03, t3[0], a0); a1 = fmaf(e13, t3[LSTR], a1);
          accc[0] = a0; accc[1] = a1;
        } else {
          // only tap row 48 (q==0, reg 0) is real in M-tile 3
          const float* t0 = base + offs[12];
          float e0 = (q == 0) ? __builtin_amdgcn_exp2f(C0[0]) : 0.f;
          float e1 = (q == 0) ? __builtin_amdgcn_exp2f(C1[0]) : 0.f;
          if (FIRST) { zacc[0] += e0; zacc[1] += e1; }
          accc[0] = fmaf(e0, t0[0], accc[0]);
          accc[1] = fmaf(e1, t0[LSTR], accc[1]);
        }
      }
      // channel c complete: reduce across quads, emit
#pragma unroll
      for (int t = 0; t < 2; ++t) {
        float v = accc[t];
        v += __shfl_xor(v, 16, 64);
        v += __shfl_xor(v, 32, 64);
        if (FINAL) {
          res[t] = fmaf(w_td[c0 + c], v, res[t]);
        } else {
          int p = (y0 + wv * 4 + np * 2 + t) * WW + (x0 + col);
          if (lane < 16) dst[((size_t)b * CC + c0 + c) * HWSZ + p] = v;
        }
        accc[t] = 0.f;
      }
      base += CSTR;
    }
    // pass tail: z (FIRST) / fused to_depth atomic accumulate (FINAL)
#pragma unroll
    for (int t = 0; t < 2; ++t) {
      int p = (y0 + wv * 4 + np * 2 + t) * WW + (x0 + col);
      if (FIRST) {
        float z = zacc[t];
        z += __shfl_xor(z, 16, 64);
        z += __shfl_xor(z, 32, 64);
        if (lane < 16) part[(size_t)g * BB * HWSZ + b * HWSZ + p] = z;
      }
      if (FINAL) {
        if (lane < 16) {
          float iz = invZ[b * HWSZ + p];
          atomicAdd(&outp[(size_t)b * HWSZ + p], res[t] * iz);
        }
      }
    }
  }
}

// invZ = 1/sum_g zpart (texture-only -> iteration-invariant); also init
// out = b_td so the FINAL dispatch can accumulate per-group via atomics.
__global__ __launch_bounds__(256) void k_zred(const float* __restrict__ zpart,
                                              float* __restrict__ invZ,
                                              const float* __restrict__ b_td,
                                              float* __restrict__ outp) {
  int t = blockIdx.x * 256 + threadIdx.x;
  float z = 0.f;
#pragma unroll
  for (int g = 0; g < G; ++g) z += zpart[(size_t)g * BB * HWSZ + t];
  invZ[t] = 1.f / z;
  outp[t] = b_td[0];
}

// ---------------------------------------------------------------------------
extern "C" void kernel_launch(void* const* d_in, const int* in_sizes, int n_in,
                              void* d_out, int out_size, void* d_ws, size_t ws_size,
                              hipStream_t stream) {
  const float* depth = (const float*)d_in[0];
  const float* tex   = (const float*)d_in[1];
  const float* w_dp  = (const float*)d_in[2];
  const float* b_dp  = (const float*)d_in[3];
  const float* w_kp  = (const float*)d_in[4];
  const float* b_kp  = (const float*)d_in[5];
  const float* w_td  = (const float*)d_in[6];
  const float* b_td  = (const float*)d_in[7];
  float* out = (float*)d_out;

  // ws: bufA/bufB (12.58 MB ea) + part (4.19 MB) + invZ (0.5 MB)
  //     + wsW (0.2 MB) + wsB (16.78 MB)  => ~47 MB
  char* ws = (char*)d_ws;
  const size_t buf_b = (size_t)BB * CC * HWSZ * 4;
  float* bufA = (float*)ws;
  float* bufB = (float*)(ws + buf_b);
  float* part = (float*)(ws + 2 * buf_b);
  float* invZ = (float*)(ws + 2 * buf_b + (size_t)G * BB * HWSZ * 4);
  short* wsW  = (short*)(ws + 2 * buf_b + (size_t)G * BB * HWSZ * 4 +
                         (size_t)BB * HWSZ * 4);
  short* wsB  = (short*)(ws + 2 * buf_b + (size_t)G * BB * HWSZ * 4 +
                         (size_t)BB * HWSZ * 4 + 192 * 512 * 2);

  k_setup<<<dim3(192 + 512), dim3(256), 0, stream>>>(w_kp, b_kp, tex, wsW, wsB);

  dim3 grid(WW / 16, HH / 16, BB * G), blk(256);
  dim3 grid1(BB * HWSZ / 256), blk1(256);

  // iter1: fused depth_latent; emits unnormalized acc + partial z
  k_diffuse_m<true, false><<<grid, blk, 0, stream>>>(
      depth, nullptr, nullptr, w_dp, b_dp, wsW, wsB, bufB, part, w_td, nullptr);
  k_zred<<<grid1, blk1, 0, stream>>>(part, invZ, b_td, out);
  // iters 2,3: unnormalized ping-pong, invZ folded into staging
  k_diffuse_m<false, false><<<grid, blk, 0, stream>>>(
      depth, bufB, invZ, w_dp, b_dp, wsW, wsB, bufA, part, w_td, nullptr);
  k_diffuse_m<false, false><<<grid, blk, 0, stream>>>(
      depth, bufA, invZ, w_dp, b_dp, wsW, wsB, bufB, part, w_td, nullptr);
  // iter4: fused to_depth, atomic accumulate into out (pre-init by k_zred)
  k_diffuse_m<false, true><<<grid, blk, 0, stream>>>(
      depth, bufB, invZ, w_dp, b_dp, wsW, wsB, nullptr, part, w_td, out);
}